// Round 1
// baseline (358.515 us; speedup 1.0000x reference)
//
#include <hip/hip_runtime.h>
#include <hip/hip_bf16.h>

#define LDST 136                       // padded row stride (bf16) for 128-wide tiles
#define CHUNK_ELEMS (128 * LDST)       // 17408 bf16 = 34816 B per staged K-chunk

typedef __bf16 bf16x8 __attribute__((ext_vector_type(8)));
typedef float  f32x4  __attribute__((ext_vector_type(4)));

#if defined(__has_builtin)
#if __has_builtin(__builtin_amdgcn_global_load_lds)
#define USE_ASYNC_LDS 1
#endif
#endif

// ---------------- prep: weights -> bf16, B-operand layout [chunk][n][k] ----------------
// chunks: 0-2 ne_w (K=384), 3 ne1_w, 4-5 att1_w (K=256), 6 att2_w
__global__ void prep_weights_kernel(const float* __restrict__ ne_w,
                                    const float* __restrict__ ne1_w,
                                    const float* __restrict__ att1_w,
                                    const float* __restrict__ att2_w,
                                    __hip_bfloat16* __restrict__ wout) {
  int idx = blockIdx.x * blockDim.x + threadIdx.x;
  const int TOT = 7 * CHUNK_ELEMS;
  if (idx >= TOT) return;
  int chunk = idx / CHUNK_ELEMS;
  int r = idx - chunk * CHUNK_ELEMS;
  int n = r / LDST;
  int kk = r - n * LDST;
  const float* src; int c;
  if      (chunk < 3) { src = ne_w;   c = chunk;     }
  else if (chunk < 4) { src = ne1_w;  c = 0;         }
  else if (chunk < 6) { src = att1_w; c = chunk - 4; }
  else                { src = att2_w; c = 0;         }
  float v = (kk < 128) ? src[(c * 128 + kk) * 128 + n] : 0.0f;
  wout[idx] = __float2bfloat16(v);
}

// ---------------- helpers ----------------
__device__ __forceinline__ unsigned short bf_bits(float x) {
  return __builtin_bit_cast(unsigned short, __float2bfloat16(x));
}

__device__ __forceinline__ void stage_chunk(__hip_bfloat16* sW,
                                            const __hip_bfloat16* __restrict__ src,
                                            int tid) {
#ifdef USE_ASYNC_LDS
  for (int g = tid; g < CHUNK_ELEMS / 8; g += 512) {
    __builtin_amdgcn_global_load_lds(
        (__attribute__((address_space(1))) void*)(void*)(src + g * 8),
        (__attribute__((address_space(3))) void*)(void*)(sW + g * 8), 16, 0, 0);
  }
#else
  const uint4* s4 = (const uint4*)src;
  uint4* d4 = (uint4*)sW;
  for (int g = tid; g < CHUNK_ELEMS / 8; g += 512) d4[g] = s4[g];
#endif
}

// A from sIn rows (stride LDST), B from sW [n][k]; wave tile 32(m) x 64(n)
__device__ __forceinline__ void mfma_chunk(const __hip_bfloat16* sIn,
                                           const __hip_bfloat16* sW,
                                           f32x4 acc[2][4], int m32, int nh, int lane) {
  const int mr = lane & 15;
  const int kq = (lane >> 4) << 3;
#pragma unroll
  for (int ks = 0; ks < 4; ++ks) {
    const int kk = ks * 32 + kq;
    bf16x8 a0 = *(const bf16x8*)(sIn + (m32 * 32 + mr) * LDST + kk);
    bf16x8 a1 = *(const bf16x8*)(sIn + (m32 * 32 + 16 + mr) * LDST + kk);
#pragma unroll
    for (int nt = 0; nt < 4; ++nt) {
      const int n = nh * 64 + nt * 16 + mr;
      bf16x8 b = *(const bf16x8*)(sW + n * LDST + kk);
      acc[0][nt] = __builtin_amdgcn_mfma_f32_16x16x32_bf16(a0, b, acc[0][nt], 0, 0, 0);
      acc[1][nt] = __builtin_amdgcn_mfma_f32_16x16x32_bf16(a1, b, acc[1][nt], 0, 0, 0);
    }
  }
}

// A rows are all the same vector (user embedding broadcast over neighbors)
__device__ __forceinline__ void mfma_chunk_bA(const __hip_bfloat16* sUvec,
                                              const __hip_bfloat16* sW,
                                              f32x4 acc[2][4], int nh, int lane) {
  const int mr = lane & 15;
  const int kq = (lane >> 4) << 3;
#pragma unroll
  for (int ks = 0; ks < 4; ++ks) {
    const int kk = ks * 32 + kq;
    bf16x8 a = *(const bf16x8*)(sUvec + kk);
#pragma unroll
    for (int nt = 0; nt < 4; ++nt) {
      const int n = nh * 64 + nt * 16 + mr;
      bf16x8 b = *(const bf16x8*)(sW + n * LDST + kk);
      acc[0][nt] = __builtin_amdgcn_mfma_f32_16x16x32_bf16(a, b, acc[0][nt], 0, 0, 0);
      acc[1][nt] = __builtin_amdgcn_mfma_f32_16x16x32_bf16(a, b, acc[1][nt], 0, 0, 0);
    }
  }
}

// bias + relu + bf16 store; C/D layout: col=lane&15, row=(lane>>4)*4+reg  [m89/m91]
__device__ __forceinline__ void epilogue(f32x4 acc[2][4], const float* __restrict__ bias,
                                         __hip_bfloat16* sOut, int m32, int nh, int lane) {
  const int cb = nh * 64 + (lane & 15);
  const int rb = (lane >> 4) << 2;
#pragma unroll
  for (int nt = 0; nt < 4; ++nt) {
    const int col = cb + nt * 16;
    const float bv = bias[col];
#pragma unroll
    for (int mt = 0; mt < 2; ++mt) {
#pragma unroll
      for (int r = 0; r < 4; ++r) {
        const int row = m32 * 32 + mt * 16 + rb + r;
        float v = fmaxf(acc[mt][nt][r] + bv, 0.0f);
        sOut[row * LDST + col] = __float2bfloat16(v);
      }
    }
  }
}

// ---------------- main fused kernel: 1 block = 2 users, M=128 rows (64/user, 50 real) ----------------
__global__ __launch_bounds__(512) void graphdec_main(
    const float* __restrict__ u2e, const float* __restrict__ i2e,
    const float* __restrict__ r2e, const float* __restrict__ t2e,
    const float* __restrict__ ne_b, const float* __restrict__ ne1_b,
    const float* __restrict__ att1_b, const float* __restrict__ att2_b,
    const float* __restrict__ att3_w, const float* __restrict__ att3_b,
    const float* __restrict__ lin_w, const float* __restrict__ lin_b,
    const float* __restrict__ w1_w, const float* __restrict__ w1_b,
    const float* __restrict__ bn1_g, const float* __restrict__ bn1_b,
    const float* __restrict__ bn1_m, const float* __restrict__ bn1_v,
    const float* __restrict__ w2_w, const float* __restrict__ w2_b,
    const float* __restrict__ bn2_g, const float* __restrict__ bn2_b,
    const float* __restrict__ bn2_m, const float* __restrict__ bn2_v,
    const float* __restrict__ w3_w, const float* __restrict__ w3_b,
    const int* __restrict__ user_idx, const int* __restrict__ item_idx,
    const int* __restrict__ rat_idx, const int* __restrict__ time_idx,
    const __hip_bfloat16* __restrict__ wprep, float* __restrict__ out) {
  __shared__ __align__(16) __hip_bfloat16 sW[CHUNK_ELEMS];   // staged weight chunk
  __shared__ __align__(16) __hip_bfloat16 sA[CHUNK_ELEMS];   // gather chunks; later a1
  __shared__ __align__(16) __hip_bfloat16 sB1[CHUNK_ELEMS];  // x1; later a2
  __shared__ __align__(16) __hip_bfloat16 sX[CHUNK_ELEMS];   // final x (persists to pooling)
  __shared__ __align__(16) __hip_bfloat16 sU[2 * LDST];
  __shared__ float sUf[2 * 128];
  __shared__ int   sIdx[3 * 128];
  __shared__ float sAtt3[128];
  __shared__ float sLogit[128];
  __shared__ float sAtt[128];
  __shared__ float sPooled[2 * 128];
  __shared__ float sComb[2 * 128];
  __shared__ float sH1[2 * 32];
  __shared__ float sH2[2 * 16];

  const int tid  = threadIdx.x;
  const int lane = tid & 63;
  const int wid  = tid >> 6;
  const int m32  = wid & 3;   // which 32-row group of M=128
  const int nh   = wid >> 2;  // which 64-col half of N=128
  const int ub0  = blockIdx.x * 2;

  // ---- preload indices, user embeddings, att3 vector ----
  if (tid < 384) {
    int c = tid >> 7, row = tid & 127, l = row & 63, u = row >> 6;
    int v = 0;
    if (l < 50) {
      const int* p = (c == 0) ? item_idx : (c == 1) ? rat_idx : time_idx;
      v = p[(ub0 + u) * 50 + l];
    }
    sIdx[tid] = v;
  }
  if (tid >= 384 && tid < 512) sAtt3[tid - 384] = att3_w[tid - 384];
  if (tid < 256) {
    int u = tid >> 7, d = tid & 127;
    float uv = u2e[user_idx[ub0 + u] * 128 + d];
    sUf[u * 128 + d] = uv;
    sU[u * LDST + d] = __float2bfloat16(uv);
  }
  __syncthreads();

  // gather one 128-wide K-chunk of the neighbor concat into sA (bf16), zero pad rows
  auto gather = [&](int c, const float* __restrict__ tab) {
    const float4* t4 = (const float4*)tab;
    for (int g = tid; g < 4096; g += 512) {       // 128 rows x 32 float4
      int row = g >> 5, q4 = g & 31;
      int l = row & 63;
      float4 v = {0.f, 0.f, 0.f, 0.f};
      if (l < 50) v = t4[(long)sIdx[c * 128 + row] * 32 + q4];
      ushort4 pk;
      pk.x = bf_bits(v.x); pk.y = bf_bits(v.y); pk.z = bf_bits(v.z); pk.w = bf_bits(v.w);
      *(ushort4*)(sA + row * LDST + q4 * 4) = pk;
    }
  };

  f32x4 acc[2][4];
  const f32x4 zf = {0.f, 0.f, 0.f, 0.f};
  auto zacc = [&]() {
#pragma unroll
    for (int i = 0; i < 2; ++i)
#pragma unroll
      for (int j = 0; j < 4; ++j) acc[i][j] = zf;
  };

  // ===== layer ne: x1 = relu(concat(i2e,r2e,t2e) @ ne_w + ne_b), K=384 = 3 table chunks =====
  zacc();
  for (int c = 0; c < 3; ++c) {
    gather(c, c == 0 ? i2e : (c == 1 ? r2e : t2e));
    stage_chunk(sW, wprep + c * CHUNK_ELEMS, tid);
    __syncthreads();
    mfma_chunk(sA, sW, acc, m32, nh, lane);
    __syncthreads();
  }
  epilogue(acc, ne_b, sB1, m32, nh, lane);
  __syncthreads();

  // ===== layer ne1: x = relu(x1 @ ne1_w + ne1_b), K=128 =====
  zacc();
  stage_chunk(sW, wprep + 3 * CHUNK_ELEMS, tid);
  __syncthreads();
  mfma_chunk(sB1, sW, acc, m32, nh, lane);
  __syncthreads();
  epilogue(acc, ne1_b, sX, m32, nh, lane);
  __syncthreads();

  // ===== att1: a1 = relu(concat(x, u) @ att1_w + att1_b), K=256 (chunk0=x, chunk1=u bcast) =====
  zacc();
  stage_chunk(sW, wprep + 4 * CHUNK_ELEMS, tid);
  __syncthreads();
  mfma_chunk(sX, sW, acc, m32, nh, lane);
  __syncthreads();
  stage_chunk(sW, wprep + 5 * CHUNK_ELEMS, tid);
  __syncthreads();
  mfma_chunk_bA(sU + (m32 >> 1) * LDST, sW, acc, nh, lane);
  __syncthreads();
  epilogue(acc, att1_b, sA, m32, nh, lane);
  __syncthreads();

  // ===== att2: a2 = relu(a1 @ att2_w + att2_b), K=128 =====
  zacc();
  stage_chunk(sW, wprep + 6 * CHUNK_ELEMS, tid);
  __syncthreads();
  mfma_chunk(sA, sW, acc, m32, nh, lane);
  __syncthreads();
  epilogue(acc, att2_b, sB1, m32, nh, lane);
  __syncthreads();

  // ===== attention logits (fp32 dot over a2) =====
  if (tid < 128) {
    int u = tid >> 6, l = tid & 63;
    float v = -1e30f;
    if (l < 50) {
      float s = att3_b[0];
      const __hip_bfloat16* row = sB1 + (u * 64 + l) * LDST;
      for (int k = 0; k < 128; ++k) s += __bfloat162float(row[k]) * sAtt3[k];
      v = s;
    }
    sLogit[tid] = v;
  }
  __syncthreads();

  // ===== softmax over 50 neighbors: wave 0 -> user0, wave 1 -> user1 =====
  if (wid < 2) {
    float v = sLogit[wid * 64 + lane];
    float m = v;
    for (int off = 32; off > 0; off >>= 1) m = fmaxf(m, __shfl_xor(m, off));
    float e = (lane < 50) ? expf(v - m) : 0.f;
    float s = e;
    for (int off = 32; off > 0; off >>= 1) s += __shfl_xor(s, off);
    sAtt[wid * 64 + lane] = e / s;
  }
  __syncthreads();

  // ===== pooled = sum_l att[l] * x[l,:] =====
  if (tid < 256) {
    int u = tid >> 7, d = tid & 127;
    float s = 0.f;
    for (int l = 0; l < 50; ++l)
      s += sAtt[u * 64 + l] * __bfloat162float(sX[(u * 64 + l) * LDST + d]);
    sPooled[u * 128 + d] = s;
  }
  __syncthreads();

  // ===== comb = relu(concat(u, pooled) @ lin_w + lin_b), fp32 =====
  if (tid < 256) {
    int u = tid >> 7, d = tid & 127;
    float s = lin_b[d];
    for (int k = 0; k < 128; ++k) s += sUf[u * 128 + k] * lin_w[k * 128 + d];
    for (int k = 0; k < 128; ++k) s += sPooled[u * 128 + k] * lin_w[(128 + k) * 128 + d];
    sComb[u * 128 + d] = fmaxf(s, 0.f);
  }
  __syncthreads();

  // ===== head: 128 -> 32 (bn1) -> 16 (bn2) -> 1, fp32 =====
  if (tid < 64) {
    int u = tid >> 5, j = tid & 31;
    float s = w1_b[j];
    for (int k = 0; k < 128; ++k) s += sComb[u * 128 + k] * w1_w[k * 32 + j];
    s = (s - bn1_m[j]) * rsqrtf(bn1_v[j] + 1e-5f) * bn1_g[j] + bn1_b[j];
    sH1[u * 32 + j] = fmaxf(s, 0.f);
  }
  __syncthreads();
  if (tid < 32) {
    int u = tid >> 4, j = tid & 15;
    float s = w2_b[j];
    for (int k = 0; k < 32; ++k) s += sH1[u * 32 + k] * w2_w[k * 16 + j];
    s = (s - bn2_m[j]) * rsqrtf(bn2_v[j] + 1e-5f) * bn2_g[j] + bn2_b[j];
    sH2[u * 16 + j] = fmaxf(s, 0.f);
  }
  __syncthreads();
  if (tid < 2) {
    float s = w3_b[0];
    for (int k = 0; k < 16; ++k) s += sH2[tid * 16 + k] * w3_w[k];
    out[ub0 + tid] = s;
  }
}

extern "C" void kernel_launch(void* const* d_in, const int* in_sizes, int n_in,
                              void* d_out, int out_size, void* d_ws, size_t ws_size,
                              hipStream_t stream) {
  const float* u2e    = (const float*)d_in[0];
  const float* i2e    = (const float*)d_in[1];
  const float* r2e    = (const float*)d_in[2];
  const float* t2e    = (const float*)d_in[3];
  const float* ne_w   = (const float*)d_in[4];
  const float* ne_b   = (const float*)d_in[5];
  const float* ne1_w  = (const float*)d_in[6];
  const float* ne1_b  = (const float*)d_in[7];
  const float* att1_w = (const float*)d_in[8];
  const float* att1_b = (const float*)d_in[9];
  const float* att2_w = (const float*)d_in[10];
  const float* att2_b = (const float*)d_in[11];
  const float* att3_w = (const float*)d_in[12];
  const float* att3_b = (const float*)d_in[13];
  const float* lin_w  = (const float*)d_in[14];
  const float* lin_b  = (const float*)d_in[15];
  const float* w1_w   = (const float*)d_in[16];
  const float* w1_b   = (const float*)d_in[17];
  const float* bn1_g  = (const float*)d_in[18];
  const float* bn1_b  = (const float*)d_in[19];
  const float* bn1_m  = (const float*)d_in[20];
  const float* bn1_v  = (const float*)d_in[21];
  const float* w2_w   = (const float*)d_in[22];
  const float* w2_b   = (const float*)d_in[23];
  const float* bn2_g  = (const float*)d_in[24];
  const float* bn2_b  = (const float*)d_in[25];
  const float* bn2_m  = (const float*)d_in[26];
  const float* bn2_v  = (const float*)d_in[27];
  const float* w3_w   = (const float*)d_in[28];
  const float* w3_b   = (const float*)d_in[29];
  const int* user_idx = (const int*)d_in[30];
  const int* item_idx = (const int*)d_in[31];
  const int* rat_idx  = (const int*)d_in[32];
  const int* time_idx = (const int*)d_in[33];
  __hip_bfloat16* wprep = (__hip_bfloat16*)d_ws;
  float* out = (float*)d_out;

  const int prep_tot = 7 * CHUNK_ELEMS;
  prep_weights_kernel<<<(prep_tot + 255) / 256, 256, 0, stream>>>(ne_w, ne1_w, att1_w,
                                                                  att2_w, wprep);
  graphdec_main<<<2048, 512, 0, stream>>>(
      u2e, i2e, r2e, t2e, ne_b, ne1_b, att1_b, att2_b, att3_w, att3_b, lin_w, lin_b,
      w1_w, w1_b, bn1_g, bn1_b, bn1_m, bn1_v, w2_w, w2_b, bn2_g, bn2_b, bn2_m, bn2_v,
      w3_w, w3_b, user_idx, item_idx, rat_idx, time_idx, wprep, out);
}